// Round 7
// baseline (45.358 us; speedup 1.0000x reference)
//
#include <hip/hip_runtime.h>
#include <float.h>

// ROI adaptive max-pool 7x7. features [512,64,64] fp32, 1024 ROIs.
// Phase 1: transpose features to [H][W][C] (channel-contiguous) in d_ws.
// Phase 2: wave = (roi, 64 channels); lane = channel. Row phase is
// branch-free: all 9 clamped column loads issue unconditionally (clamped
// duplicates are never selected by the static predicate tree), addresses
// are 9 precomputed VGPR offsets + one scalar row-base bump. Rows are
// 2-deep ping-ponged (named va/vb, statically indexed) so row t+1 loads
// overlap row t compute (counted vmcnt). Store via per-wave LDS transpose.
constexpr int CC = 512, HH = 64, WW = 64, HW = HH * WW;
#define NEG (-FLT_MAX)
typedef float f4 __attribute__((ext_vector_type(4)));

// ---------- phase 1: [C][HW] -> [HW][C] ----------
__global__ __launch_bounds__(256) void transpose_kernel(
    const float* __restrict__ f, float* __restrict__ ft)
{
    __shared__ float tile[64][65];
    int bs = blockIdx.x & 63;            // hw tile (4096/64)
    int bc = blockIdx.x >> 6;            // c tile (512/64)
    int tx = threadIdx.x & 63, ty0 = threadIdx.x >> 6;
#pragma unroll
    for (int k = 0; k < 16; ++k) {
        int c = k * 4 + ty0;
        tile[c][tx] = f[(size_t)(bc * 64 + c) * HW + bs * 64 + tx];  // coalesced read
    }
    __syncthreads();
#pragma unroll
    for (int k = 0; k < 16; ++k) {
        int s = k * 4 + ty0;
        ft[(size_t)(bs * 64 + s) * CC + bc * 64 + tx] = tile[tx][s]; // coalesced write
    }
}

// static per-bin cell ranges: bin j can only touch cells
// k in [floor(2j/7), ceil(9(j+1)/7)) for w_len in [2,9] -> 36 terms total.
#define KMIN(j) ((2 * (j)) / 7)
#define KMAX(j) ((9 * ((j) + 1) + 6) / 7)

__device__ __forceinline__ void loadrow(float (&V)[9], const char* rb,
                                        const int (&voff)[9])
{
#pragma unroll
    for (int k = 0; k < 9; ++k)
        V[k] = *(const float*)(rb + voff[k]);
}

__device__ __forceinline__ void compute_row(
    const float (&V)[9], int h, float (&acc)[7][7],
    const int (&hs)[7], const int (&he)[7],
    const int (&s_)[7], const int (&e_)[7])
{
    float m[7];
#pragma unroll
    for (int j = 0; j < 7; ++j) {
        float a = NEG;
#pragma unroll
        for (int k = KMIN(j); k < KMAX(j); ++k) {
            bool p = (k >= s_[j]) && (k < e_[j]);   // wave-uniform
            a = fmaxf(a, p ? V[k] : NEG);
        }
        m[j] = a;
    }
#pragma unroll
    for (int i = 0; i < 7; ++i) {
        if (h >= hs[i] && h < he[i]) {              // uniform scalar branch
#pragma unroll
            for (int j = 0; j < 7; ++j)
                acc[i][j] = fmaxf(acc[i][j], m[j]);
        }
    }
}

// ---------- phase 2: pool from [HW][C] ----------
__global__ __launch_bounds__(256) void pool_kernel(
    const float* __restrict__ ft,        // [H][W][C]
    const int4*  __restrict__ rois,      // [R] (x1,y1,x2,y2) image px
    float* __restrict__ out,             // [R,C,7,7]
    int ngroups)
{
    __shared__ __align__(16) float lds[4][32 * 49];
    int wslot = threadIdx.x >> 6;
    int wid = __builtin_amdgcn_readfirstlane(blockIdx.x * 4 + wslot);
    if (wid >= ngroups) return;
    int lane = threadIdx.x & 63;

    int r  = wid >> 3;                   // 8 channel-groups per ROI
    int c0 = (wid & 7) << 6;

    int4 roi = rois[r];                  // uniform -> s_load
    // (px * 1/16.f) truncated == px >> 4 for px in [0,1024): exact in fp32.
    int x1 = roi.x >> 4, y1 = roi.y >> 4, x2 = roi.z >> 4, y2 = roi.w >> 4;
    int hl = y2 - y1 + 1, wl = x2 - x1 + 1;   // 2..9 each (bw,bh >= 16 px)

    // torch adaptive bins: [floor(i*L/7), ceil((i+1)*L/7)) + offset.
    int hs[7], he[7], s_[7], e_[7];
#pragma unroll
    for (int i = 0; i < 7; ++i) {
        hs[i] = y1 + (i * hl) / 7;
        he[i] = y1 + ((i + 1) * hl + 6) / 7;
        s_[i] = (i * wl) / 7;                 // cell index relative to x1
        e_[i] = ((i + 1) * wl + 6) / 7;
    }

    // 9 clamped column byte-offsets (loop-invariant VGPRs). Columns k >= wl
    // duplicate column wl-1: in-bounds, and never selected by the predicate
    // tree (e_[j] <= wl), so their values are don't-care.
    int voff[9];
#pragma unroll
    for (int k = 0; k < 9; ++k) {
        int col = x1 + min(k, wl - 1);
        voff[k] = (col * CC + lane) * 4;
    }

    float acc[7][7];
#pragma unroll
    for (int i = 0; i < 7; ++i)
#pragma unroll
        for (int j = 0; j < 7; ++j) acc[i][j] = NEG;

    const int rowstep = WW * CC * 4;
    const char* rb = (const char*)(ft + c0) + (size_t)y1 * rowstep;

    // 2-deep ping-pong over rows (hl >= 2 always).
    float va[9], vb[9];
    loadrow(va, rb, voff);
    const char* rbn = rb + rowstep;
    int t = 0;
    for (;;) {
        if (t + 1 < hl) loadrow(vb, rbn, voff);
        compute_row(va, y1 + t, acc, hs, he, s_, e_);
        ++t; if (t == hl) break;
        rbn += rowstep;
        if (t + 1 < hl) loadrow(va, rbn, voff);
        compute_row(vb, y1 + t, acc, hs, he, s_, e_);
        ++t; if (t == hl) break;
        rbn += rowstep;
    }

    // Store: transpose [64ch][49] -> flat [c][bin] via LDS, 2 rounds of 32ch.
    float* L  = lds[wslot];
    float* ob = out + ((size_t)r * CC + c0) * 49;
#pragma unroll
    for (int round = 0; round < 2; ++round) {
        if ((lane >> 5) == round) {
            float* p = L + (lane & 31) * 49;      // stride 49 (odd): conflict-free
#pragma unroll
            for (int i = 0; i < 7; ++i)
#pragma unroll
                for (int j = 0; j < 7; ++j) p[i * 7 + j] = acc[i][j];
        }
        asm volatile("s_waitcnt lgkmcnt(0)" ::: "memory");
        float* og = ob + round * 1568;            // 1568 floats contiguous
#pragma unroll
        for (int s = 0; s < 6; ++s) {             // 6 x (64 lanes x dwordx4)
            int idx = s * 64 + lane;
            *(f4*)(og + idx * 4) = *(const f4*)(L + idx * 4);
        }
        if (lane < 8) {                           // 392 = 6*64 + 8 tail
            int idx = 384 + lane;
            *(f4*)(og + idx * 4) = *(const f4*)(L + idx * 4);
        }
        asm volatile("s_waitcnt lgkmcnt(0)" ::: "memory"); // reads done before re-write
    }
}

// ---------- fallback (R4, proven): used only if ws_size < 8 MB ----------
__global__ __launch_bounds__(256) void roi_pool_direct(
    const float* __restrict__ features, const int4* __restrict__ rois,
    float* __restrict__ out, int ngroups)
{
    int wid = __builtin_amdgcn_readfirstlane(
        blockIdx.x * (blockDim.x >> 6) + (threadIdx.x >> 6));
    if (wid >= ngroups) return;
    int lane = threadIdx.x & 63;
    if (lane >= 49) return;
    int r = wid >> 4, c0 = (wid & 15) * 32;
    int4 roi = rois[r];
    int x1 = roi.x >> 4, y1 = roi.y >> 4, x2 = roi.z >> 4, y2 = roi.w >> 4;
    int h_len = y2 - y1 + 1, w_len = x2 - x1 + 1;
    int oh = lane / 7, ow = lane - oh * 7;
    int hs = y1 + (oh * h_len) / 7, he = y1 + ((oh + 1) * h_len + 6) / 7;
    int ws = x1 + (ow * w_len) / 7, we = x1 + ((ow + 1) * w_len + 6) / 7;
    int wlst = we - 1;
    int wa = ws, wb = min(ws + 1, wlst), wc = min(ws + 2, wlst);
    bool need1 = hs + 1 < he, need2 = hs + 2 < he;
    int o0 = (hs * WW + wa) * 4, o0b = (hs * WW + wb) * 4, o0c = (hs * WW + wc) * 4;
    const char* fb = (const char*)features + (size_t)c0 * (HW * 4);
    float* ob = out + ((size_t)r * CC + c0) * 49 + lane;
#pragma unroll 4
    for (int j = 0; j < 32; ++j) {
        float a = fmaxf(fmaxf(*(const float*)(fb + o0),
                              *(const float*)(fb + o0b)),
                        *(const float*)(fb + o0c));
        if (need1) {
            a = fmaxf(a, fmaxf(fmaxf(*(const float*)(fb + o0 + WW * 4),
                                     *(const float*)(fb + o0b + WW * 4)),
                               *(const float*)(fb + o0c + WW * 4)));
        }
        if (need2) {
            a = fmaxf(a, fmaxf(fmaxf(*(const float*)(fb + o0 + 2 * WW * 4),
                                     *(const float*)(fb + o0b + 2 * WW * 4)),
                               *(const float*)(fb + o0c + 2 * WW * 4)));
        }
        *ob = a;
        fb += HW * 4;
        ob += 49;
    }
}

extern "C" void kernel_launch(void* const* d_in, const int* in_sizes, int n_in,
                              void* d_out, int out_size, void* d_ws, size_t ws_size,
                              hipStream_t stream) {
    const float* features = (const float*)d_in[0];   // [1,512,64,64] fp32
    const int4*  rois     = (const int4*)d_in[1];    // [R,4] int32
    float* out = (float*)d_out;
    int R = out_size / (CC * 49);                    // 1024

    if (ws_size >= (size_t)CC * HW * sizeof(float)) {
        float* ft = (float*)d_ws;                    // [HW][C], 8 MB
        transpose_kernel<<<512, 256, 0, stream>>>(features, ft);
        int ngroups = R * 8;                         // 64 channels per wave
        pool_kernel<<<ngroups / 4, 256, 0, stream>>>(ft, rois, out, ngroups);
    } else {
        int ngroups = R * 16;
        roi_pool_direct<<<(ngroups + 3) / 4, 256, 0, stream>>>(features, rois, out, ngroups);
    }
}